// Round 1
// 243.091 us; speedup vs baseline: 1.0169x; 1.0169x over previous
//
#include <hip/hip_runtime.h>

// QuantumMotivicTile — B=4, S=2048, H=16, hd=64, D=1024, fp32 I/O.
// final = softmax(q k^T / 8) @ v'' + ecv
//   Aq = QS·Wq·Wi (QS = 0.125·log2e → scores in log2 domain, exp2 softmax),
//   Ak = Wk·Wi (bias cancels in softmax), Av = M·Wv·Wi, M = Wmi·Wm·Wci·Wc,
//   ecv = M·(Wv·bi+bv) + cvec.
// R6: attn P/Q stay in registers (v_cvt_pk_bf16_f32 + v_permlane32_swap_b32
// replaces pk2r+LDS round trip); defer-max rescale (THR=8, log2 domain);
// XOR-swizzled K/V LDS (stride 64, conflict-free); combine split into 3 role
// blocks; kv 1 tile/block grid(32,64).

#define SEQ 2048
#define DM  1024
#define HD  64
#define QS  0.180336880111120429f  // 0.125 * log2(e)
#define THR 8.0f                   // defer-max threshold (log2 units)

typedef short bf16x8 __attribute__((ext_vector_type(8)));
typedef unsigned short u16x8 __attribute__((ext_vector_type(8)));
typedef float f32x16 __attribute__((ext_vector_type(16)));

#define MFMA32 __builtin_amdgcn_mfma_f32_32x32x16_bf16

#if defined(__has_builtin)
#if __has_builtin(__builtin_amdgcn_exp2f)
#define EXP2(x) __builtin_amdgcn_exp2f(x)
#endif
#endif
#ifndef EXP2
#define EXP2(x) exp2f(x)
#endif

// ws layout:
//   float [0..63] bq' (×QS), [64..127] ecv
//   ushort base wsu = (ushort*)(ws+128):
//     [0..4095]      Aq (×QS) row-major [dout][din]
//     [4096..8191]   Ak row-major
//     [8192..12287]  Av row-major
//     [12288 ..)     Kg[bh][key][dout]   (64*2048*64)
//     [+8388608 ..)  Vtg[bh][dout][key]  (64*64*2048)
#define KG_OFF  12288
#define VG_OFF  (12288 + 8388608)
#define WS_NEED ((size_t)512 + 2ull * (12288 + 2ull * 8388608))

__device__ __forceinline__ unsigned short f2bf(float f) {
    unsigned int v = __float_as_uint(f);
    unsigned int r = v + 0x7FFFu + ((v >> 16) & 1u);
    return (unsigned short)(r >> 16);
}
__device__ __forceinline__ unsigned int pk2r(float a, float b) {
    return __builtin_amdgcn_perm(__float_as_uint(b) + 0x8000u,
                                 __float_as_uint(a) + 0x8000u, 0x07060302u);
}
__device__ __forceinline__ unsigned int pk2t(float a, float b) {
    return __builtin_amdgcn_perm(__float_as_uint(b), __float_as_uint(a), 0x07060302u);
}
// {lo: bf16(a), hi: bf16(b)} — RNE, 1 VALU op (replaces 3-op pk2r)
__device__ __forceinline__ unsigned int cvtpk(float a, float b) {
    unsigned int r;
    asm("v_cvt_pk_bf16_f32 %0, %1, %2" : "=v"(r) : "v"(a), "v"(b));
    return r;
}
// a' = {a.lanes0-31, b.lanes0-31}; b' = {a.lanes32-63, b.lanes32-63}
__device__ __forceinline__ void swap32(unsigned int& a, unsigned int& b) {
    asm("v_permlane32_swap_b32 %0, %1" : "+v"(a), "+v"(b));
}
__device__ __forceinline__ f32x16 z16() {
    f32x16 v;
    #pragma unroll
    for (int i = 0; i < 16; i++) v[i] = 0.f;
    return v;
}

// Convert one 32x32 MFMA C-block (col=lane&31, row=(reg&3)+8*(reg>>2)+4*(lane>>5))
// into two A/B-operand fragments: fA covers rows 0..15, fB rows 16..31,
// each lane ending with 8 contiguous row-values of its column.
//   regs 0-3 of lo-lane = rows 0-3, of hi-lane = rows 4-7; swap with regs 4-7
//   (rows 8-11 / 12-15) across the lane<32 / lane>=32 halves.
__device__ __forceinline__ void pack2(const f32x16 s, bf16x8& fA, bf16x8& fB) {
    union { bf16x8 v; unsigned int u[4]; } a, b;
    a.u[0] = cvtpk(s[0], s[1]);   a.u[1] = cvtpk(s[2], s[3]);
    a.u[2] = cvtpk(s[4], s[5]);   a.u[3] = cvtpk(s[6], s[7]);
    b.u[0] = cvtpk(s[8], s[9]);   b.u[1] = cvtpk(s[10], s[11]);
    b.u[2] = cvtpk(s[12], s[13]); b.u[3] = cvtpk(s[14], s[15]);
    swap32(a.u[0], a.u[2]); swap32(a.u[1], a.u[3]);
    swap32(b.u[0], b.u[2]); swap32(b.u[1], b.u[3]);
    fA = a.v; fB = b.v;
}

// acc[0..16) = (wrow · L)[i0..i0+16); wrow/L in LDS, row stride 68 floats
__device__ __forceinline__ void mm16L(const float* __restrict__ wrow,
                                      const float* __restrict__ L, int i0,
                                      float* __restrict__ acc) {
    #pragma unroll
    for (int ii = 0; ii < 16; ii++) acc[ii] = 0.f;
    for (int t = 0; t < 64; t += 4) {
        float4 w4 = *(const float4*)(wrow + t);
        #pragma unroll
        for (int d = 0; d < 4; d++) {
            float wv = (d == 0) ? w4.x : (d == 1) ? w4.y : (d == 2) ? w4.z : w4.w;
            const float* lr = L + (t + d) * 68 + i0;
            float4 a = *(const float4*)lr;
            float4 b = *(const float4*)(lr + 4);
            float4 c = *(const float4*)(lr + 8);
            float4 e = *(const float4*)(lr + 12);
            acc[0] += wv * a.x;  acc[1] += wv * a.y;  acc[2]  += wv * a.z;  acc[3]  += wv * a.w;
            acc[4] += wv * b.x;  acc[5] += wv * b.y;  acc[6]  += wv * b.z;  acc[7]  += wv * b.w;
            acc[8] += wv * c.x;  acc[9] += wv * c.y;  acc[10] += wv * c.z;  acc[11] += wv * c.w;
            acc[12] += wv * e.x; acc[13] += wv * e.y; acc[14] += wv * e.z;  acc[15] += wv * e.w;
        }
    }
}

// ---------------- weight folding (3 role blocks, 256 threads, all-LDS) ----------------
// role 0: Aq + bq'   role 1: Ak   role 2: Wvi -> M -> Av + ecv (chain)
__global__ __launch_bounds__(256)
void qmt_combine(const float* __restrict__ Wi,  const float* __restrict__ bi,
                 const float* __restrict__ Wq,  const float* __restrict__ bq,
                 const float* __restrict__ Wk,  const float* __restrict__ bk,
                 const float* __restrict__ Wv,  const float* __restrict__ bv,
                 const float* __restrict__ Wc,  const float* __restrict__ bc,
                 const float* __restrict__ Wci, const float* __restrict__ bci,
                 const float* __restrict__ Wm,  const float* __restrict__ bm,
                 const float* __restrict__ Wmi, const float* __restrict__ bmi,
                 float* __restrict__ ws) {
    const int tid = threadIdx.x;
    const int o = tid & 63;
    const int i0 = (tid >> 6) * 16;
    const bool lead = (tid < 64);
    const int role = blockIdx.x;

    __shared__ float Wa_s[64 * 68];
    __shared__ float Wi_s[64 * 68];
    __shared__ float Wvi_s[64 * 68];
    __shared__ float M_s[64 * 68];
    __shared__ float Wc_s[512];    // 8x64
    __shared__ float Wci_s[512];   // 64x8
    __shared__ float Wm_s[256];    // 4x64
    __shared__ float Wmi_s[256];   // 64x4
    __shared__ float bi_s[64], bvi_s[64], c1[64], c2[4];
    __shared__ float U1[32], U2[256];

    unsigned short* wsu = (unsigned short*)(ws + 128);
    const float* Wa = (role == 0) ? Wq : (role == 1) ? Wk : Wv;

    for (int i4 = tid; i4 < 1024; i4 += 256) {
        int r = i4 >> 4, c = (i4 & 15) * 4;
        *(float4*)&Wi_s[r * 68 + c] = *(const float4*)(Wi + i4 * 4);
        *(float4*)&Wa_s[r * 68 + c] = *(const float4*)(Wa + i4 * 4);
    }
    if (role == 2) {
        if (tid < 128) {
            *(float4*)&Wc_s[tid * 4]  = *(const float4*)(Wc + tid * 4);
            *(float4*)&Wci_s[tid * 4] = *(const float4*)(Wci + tid * 4);
        } else if (tid < 192) {
            int t = tid - 128;
            *(float4*)&Wm_s[t * 4]  = *(const float4*)(Wm + t * 4);
            *(float4*)&Wmi_s[t * 4] = *(const float4*)(Wmi + t * 4);
        }
    }
    if (lead) bi_s[o] = bi[o];
    __syncthreads();  // (1)

    float acc[16];
    if (role == 0) {
        // Aq = QS·Wq·Wi ; bq' = QS·(Wq·bi + bq)
        mm16L(Wa_s + o * 68, Wi_s, i0, acc);
        #pragma unroll
        for (int ii = 0; ii < 16; ii++) wsu[o * 64 + i0 + ii] = f2bf(acc[ii] * QS);
        if (lead) {
            float s = bq[o];
            for (int t = 0; t < 64; t++) s += Wa_s[o * 68 + t] * bi_s[t];
            ws[o] = s * QS;
        }
        return;
    }
    if (role == 1) {
        // Ak = Wk·Wi
        mm16L(Wa_s + o * 68, Wi_s, i0, acc);
        #pragma unroll
        for (int ii = 0; ii < 16; ii++) wsu[4096 + o * 64 + i0 + ii] = f2bf(acc[ii]);
        return;
    }
    // role 2: Wvi = Wv·Wi, bvi
    mm16L(Wa_s + o * 68, Wi_s, i0, acc);
    #pragma unroll
    for (int ii = 0; ii < 16; ii++) Wvi_s[o * 68 + i0 + ii] = acc[ii];
    if (lead) {
        float s = bv[o];
        for (int t = 0; t < 64; t++) s += Wa_s[o * 68 + t] * bi_s[t];
        bvi_s[o] = s;
    }
    // U1 = Wm·Wci (4x8)
    if (tid < 32) {
        int a = tid >> 3, c = tid & 7;
        float s = 0.f;
        for (int t = 0; t < 64; t++) s += Wm_s[a * 64 + t] * Wci_s[t * 8 + c];
        U1[a * 8 + c] = s;
    }
    __syncthreads();  // (2)
    if (lead) {
        for (int a = 0; a < 4; a++) {
            float s = 0.f;
            for (int cc = 0; cc < 8; cc++) s += U1[a * 8 + cc] * Wc_s[cc * 64 + o];
            U2[a * 64 + o] = s;
        }
        float s = bci[o];
        for (int j = 0; j < 8; j++) s += Wci_s[o * 8 + j] * bc[j];
        c1[o] = s;
    }
    __syncthreads();  // (3)
    // M = Wmi·U2
    #pragma unroll
    for (int ii = 0; ii < 16; ii++) {
        float s = 0.f;
        for (int a = 0; a < 4; a++) s += Wmi_s[o * 4 + a] * U2[a * 64 + i0 + ii];
        M_s[o * 68 + i0 + ii] = s;
    }
    if (tid < 4) {
        float s = bm[tid];
        for (int i = 0; i < 64; i++) s += Wm_s[tid * 64 + i] * c1[i];
        c2[tid] = s;
    }
    __syncthreads();  // (4)
    // Av = M·Wvi ; ecv = (Wmi·c2 + bmi) + M·bvi
    mm16L(M_s + o * 68, Wvi_s, i0, acc);
    #pragma unroll
    for (int ii = 0; ii < 16; ii++) wsu[8192 + o * 64 + i0 + ii] = f2bf(acc[ii]);
    if (lead) {
        float bvv = 0.f;
        for (int t = 0; t < 64; t++) bvv += M_s[o * 68 + t] * bvi_s[t];
        float cvv = bmi[o];
        for (int a = 0; a < 4; a++) cvv += Wmi_s[o * 4 + a] * c2[a];
        ws[64 + o] = cvv + bvv;
    }
}

// ---------------- KV prepass: grid (32, 64), 1 ktile/block ----------------
__global__ __launch_bounds__(256)
void qmt_kv(const float* __restrict__ x, float* __restrict__ ws) {
    const int tid = threadIdx.x;
    const int w = tid >> 6;
    const int lane = tid & 63;
    const int ln = lane & 31;
    const int h = lane >> 5;
    const int b = blockIdx.y >> 4;
    const int hh = blockIdx.y & 15;
    const int kt = blockIdx.x;

    const unsigned short* wsu = (const unsigned short*)(ws + 128);
    unsigned short* Kg = (unsigned short*)(ws + 128) + KG_OFF + (size_t)blockIdx.y * (2048 * 64);
    unsigned short* Vg = (unsigned short*)(ws + 128) + VG_OFF + (size_t)blockIdx.y * (64 * 2048);

    const int krl = (w >> 1) * 32 + ln;
    const int dt32 = (w & 1) * 32;

    bf16x8 akf[4], avf[4];
    #pragma unroll
    for (int c = 0; c < 4; c++) {
        int row = dt32 + ln;
        int col = c * 16 + h * 8;
        akf[c] = *(const bf16x8*)(wsu + 4096 + row * 64 + col);
        avf[c] = *(const bf16x8*)(wsu + 8192 + row * 64 + col);
    }
    bf16x8 xf[4];
    const float* xr = x + ((size_t)(b * SEQ + kt * 64 + krl) * DM + hh * HD);
    #pragma unroll
    for (int c = 0; c < 4; c++) {
        const float* p = xr + c * 16 + h * 8;
        float4 f0 = *(const float4*)p;
        float4 f1 = *(const float4*)(p + 4);
        union { bf16x8 v; unsigned int u[4]; } tt;
        tt.u[0] = pk2t(f0.x, f0.y); tt.u[1] = pk2t(f0.z, f0.w);
        tt.u[2] = pk2t(f1.x, f1.y); tt.u[3] = pk2t(f1.z, f1.w);
        xf[c] = tt.v;
    }
    f32x16 kacc = z16(), vacc = z16();
    #pragma unroll
    for (int c = 0; c < 4; c++) kacc = MFMA32(akf[c], xf[c], kacc, 0, 0, 0);
    #pragma unroll
    for (int c = 0; c < 4; c++) vacc = MFMA32(xf[c], avf[c], vacc, 0, 0, 0);
    #pragma unroll
    for (int g = 0; g < 4; g++) {
        uint2 pk_, pv_;
        pk_.x = cvtpk(kacc[4 * g + 0], kacc[4 * g + 1]);
        pk_.y = cvtpk(kacc[4 * g + 2], kacc[4 * g + 3]);
        *(uint2*)&Kg[(size_t)(kt * 64 + krl) * 64 + dt32 + 8 * g + 4 * h] = pk_;
        pv_.x = cvtpk(vacc[4 * g + 0], vacc[4 * g + 1]);
        pv_.y = cvtpk(vacc[4 * g + 2], vacc[4 * g + 3]);
        *(uint2*)&Vg[(size_t)(dt32 + ln) * 2048 + kt * 64 + (w >> 1) * 32 + 8 * g + 4 * h] = pv_;
    }
}

// ---------------- MFMA flash attention ----------------
// grid (16 q-tiles, 64 bh), 256 thr = 4 waves. QT=128, KT=64.
// P/Q fragments stay in registers (cvt_pk + permlane32_swap); K/V LDS tiles
// XOR-swizzled (stride 64 shorts, chunk ^= row&7 => conflict-free b128);
// defer-max rescale skips alpha path when no q grows its max by >THR.
__global__ __launch_bounds__(256, 4)
void qmt_attn2(const float* __restrict__ x, const float* __restrict__ wsf,
               float* __restrict__ out) {
    __shared__ __align__(16) unsigned short ks_s[64 * 64];  // K [key][dout], swizzled
    __shared__ __align__(16) unsigned short vt_s[64 * 64];  // V^T [dout][key], swizzled
    __shared__ float als_l[128];
    __shared__ float ls_l[128];

    const int tid = threadIdx.x;
    const int w = tid >> 6;
    const int lane = tid & 63;
    const int ln = lane & 31;
    const int h = lane >> 5;
    const int b = blockIdx.y >> 4;
    const int hh = blockIdx.y & 15;
    const int qbase = blockIdx.x * 128;

    const unsigned short* wsu = (const unsigned short*)(wsf + 128);
    const unsigned short* Kg = wsu + KG_OFF + (size_t)blockIdx.y * (2048 * 64);
    const unsigned short* Vg = wsu + VG_OFF + (size_t)blockIdx.y * (64 * 2048);

    const float ec0 = wsf[64 + ln];
    const float ec1 = wsf[96 + ln];

    // staging: thread handles rows (srow, srow+32), 16B column chunk (tid&7)
    const int srow = tid >> 3;
    const int scol = (tid & 7) * 8;
    const int sch = (((tid & 7) ^ (srow & 7)) * 8);  // swizzled LDS chunk (shorts)
    const int swm = ln & 7;                          // read-side swizzle mask

    // issue tile-0 staging loads early (hide under Q projection)
    u16x8 ka = *(const u16x8*)(Kg + (size_t)srow * 64 + scol);
    u16x8 kb = *(const u16x8*)(Kg + (size_t)(srow + 32) * 64 + scol);
    u16x8 va = *(const u16x8*)(Vg + (size_t)srow * 2048 + scol);
    u16x8 vb = *(const u16x8*)(Vg + (size_t)(srow + 32) * 2048 + scol);

    // ---- Q projection: Q^T = Aq·x^T (log2 scale folded in), all in registers ----
    bf16x8 qf[4];
    {
        bf16x8 xq[4];
        const float* xrow = x + ((size_t)(b * SEQ + qbase + w * 32 + ln) * DM + hh * HD);
        #pragma unroll
        for (int c = 0; c < 4; c++) {
            const float* p = xrow + c * 16 + h * 8;
            float4 f0 = *(const float4*)p;
            float4 f1 = *(const float4*)(p + 4);
            union { bf16x8 v; unsigned int u[4]; } t;
            t.u[0] = pk2t(f0.x, f0.y); t.u[1] = pk2t(f0.z, f0.w);
            t.u[2] = pk2t(f1.x, f1.y); t.u[3] = pk2t(f1.z, f1.w);
            xq[c] = t.v;
        }
        #pragma unroll
        for (int m = 0; m < 2; m++) {
            f32x16 acc;
            #pragma unroll
            for (int g = 0; g < 4; g++) {
                float4 b4 = *(const float4*)&wsf[m * 32 + 8 * g + 4 * h];
                acc[4 * g + 0] = b4.x; acc[4 * g + 1] = b4.y;
                acc[4 * g + 2] = b4.z; acc[4 * g + 3] = b4.w;
            }
            #pragma unroll
            for (int c = 0; c < 4; c++) {
                bf16x8 aq = *(const bf16x8*)(wsu + (m * 32 + ln) * 64 + c * 16 + h * 8);
                acc = MFMA32(aq, xq[c], acc, 0, 0, 0);
            }
            pack2(acc, qf[2 * m], qf[2 * m + 1]);  // dout chunks 2m, 2m+1
        }
    }

    f32x16 o0 = z16(), o1 = z16();
    float m_i = -1e30f, l_i = 0.f;

    *(u16x8*)&ks_s[srow * 64 + sch] = ka;
    *(u16x8*)&ks_s[(srow + 32) * 64 + sch] = kb;
    *(u16x8*)&vt_s[srow * 64 + sch] = va;
    *(u16x8*)&vt_s[(srow + 32) * 64 + sch] = vb;
    __syncthreads();

    for (int kt = 0; kt < SEQ / 64; kt++) {
        const bool more = (kt < SEQ / 64 - 1);
        if (more) {  // prefetch next tile into registers
            const int kn = (kt + 1) * 64;
            ka = *(const u16x8*)(Kg + (size_t)(kn + srow) * 64 + scol);
            kb = *(const u16x8*)(Kg + (size_t)(kn + srow + 32) * 64 + scol);
            va = *(const u16x8*)(Vg + (size_t)srow * 2048 + kn + scol);
            vb = *(const u16x8*)(Vg + (size_t)(srow + 32) * 2048 + kn + scol);
        }

        // ---- S^T = K·Q^T (log2 domain) ----
        f32x16 st0 = z16(), st1 = z16();
        #pragma unroll
        for (int c = 0; c < 4; c++) {
            const int ci = ((c * 2 + h) ^ swm) * 8;
            bf16x8 k0 = *(const bf16x8*)&ks_s[ln * 64 + ci];
            bf16x8 k1 = *(const bf16x8*)&ks_s[(32 + ln) * 64 + ci];
            st0 = MFMA32(k0, qf[c], st0, 0, 0, 0);
            st1 = MFMA32(k1, qf[c], st1, 0, 0, 0);
        }

        // tile max (tree, depth 5)
        float tm[8];
        #pragma unroll
        for (int i = 0; i < 8; i++)
            tm[i] = fmaxf(fmaxf(st0[i], st0[i + 8]), fmaxf(st1[i], st1[i + 8]));
        #pragma unroll
        for (int i = 0; i < 4; i++) tm[i] = fmaxf(tm[i], tm[i + 4]);
        float mx = fmaxf(fmaxf(tm[0], tm[1]), fmaxf(tm[2], tm[3]));
        mx = fmaxf(mx, __shfl_xor(mx, 32));

        // defer-max: only raise m and rescale O if some q grew by > THR
        const bool need = __any(mx > m_i + THR) != 0;
        float mn = m_i, al = 1.0f;
        if (need) {
            mn = fmaxf(m_i, mx);
            al = EXP2(m_i - mn);
            if (lane < 32) als_l[w * 32 + lane] = al;
        }

        #pragma unroll
        for (int i = 0; i < 16; i++) st0[i] = EXP2(st0[i] - mn);
        #pragma unroll
        for (int i = 0; i < 16; i++) st1[i] = EXP2(st1[i] - mn);
        float sm[8];
        #pragma unroll
        for (int i = 0; i < 8; i++)
            sm[i] = (st0[i] + st0[i + 8]) + (st1[i] + st1[i + 8]);
        #pragma unroll
        for (int i = 0; i < 4; i++) sm[i] += sm[i + 4];
        float ss = (sm[0] + sm[1]) + (sm[2] + sm[3]);
        ss += __shfl_xor(ss, 32);
        l_i = l_i * al + ss;
        m_i = mn;

        // P -> A-fragments, fully in registers
        bf16x8 pf[4];
        pack2(st0, pf[0], pf[1]);  // k chunks 0,1
        pack2(st1, pf[2], pf[3]);  // k chunks 2,3

        if (need) {  // rescale O by alpha[q]
            #pragma unroll
            for (int g = 0; g < 4; g++) {
                float4 a4 = *(const float4*)&als_l[w * 32 + 8 * g + 4 * h];
                o0[4 * g + 0] *= a4.x; o0[4 * g + 1] *= a4.y;
                o0[4 * g + 2] *= a4.z; o0[4 * g + 3] *= a4.w;
                o1[4 * g + 0] *= a4.x; o1[4 * g + 1] *= a4.y;
                o1[4 * g + 2] *= a4.z; o1[4 * g + 3] *= a4.w;
            }
        }

        // ---- O += P·V ----
        #pragma unroll
        for (int c = 0; c < 4; c++) {
            const int ci = ((c * 2 + h) ^ swm) * 8;
            bf16x8 v0 = *(const bf16x8*)&vt_s[ln * 64 + ci];
            bf16x8 v1 = *(const bf16x8*)&vt_s[(32 + ln) * 64 + ci];
            o0 = MFMA32(pf[c], v0, o0, 0, 0, 0);
            o1 = MFMA32(pf[c], v1, o1, 0, 0, 0);
        }
        __syncthreads();  // (i) all reads of ks/vt done
        if (more) {
            *(u16x8*)&ks_s[srow * 64 + sch] = ka;
            *(u16x8*)&ks_s[(srow + 32) * 64 + sch] = kb;
            *(u16x8*)&vt_s[srow * 64 + sch] = va;
            *(u16x8*)&vt_s[(srow + 32) * 64 + sch] = vb;
        }
        __syncthreads();  // (ii) next tile visible
    }

    // ---- epilogue ----
    if (lane < 32) ls_l[w * 32 + lane] = l_i;
    #pragma unroll
    for (int g = 0; g < 4; g++) {
        float4 l4 = *(const float4*)&ls_l[w * 32 + 8 * g + 4 * h];
        float4 iv = make_float4(1.f / l4.x, 1.f / l4.y, 1.f / l4.z, 1.f / l4.w);
        #pragma unroll
        for (int i = 0; i < 4; i++) {
            float ivv = (i == 0) ? iv.x : (i == 1) ? iv.y : (i == 2) ? iv.z : iv.w;
            int q = qbase + w * 32 + 8 * g + 4 * h + i;
            float* orow = out + ((size_t)(b * SEQ + q) * DM + hh * HD);
            orow[ln] = o0[4 * g + i] * ivv + ec0;
            orow[32 + ln] = o1[4 * g + i] * ivv + ec1;
        }
    }
}

// ---------------- fallback attention (in-loop KV projection) ----------------
__global__ __launch_bounds__(256, 3)
void qmt_attn_fb(const float* __restrict__ x, const float* __restrict__ wsf,
                 float* __restrict__ out) {
    __shared__ __align__(16) unsigned short ps_s[128 * 72];
    __shared__ __align__(16) unsigned short ks_s[64 * 72];
    __shared__ __align__(16) unsigned short vt_s[64 * 72];
    __shared__ float als_l[128];
    __shared__ float ls_l[128];

    const int tid = threadIdx.x;
    const int w = tid >> 6;
    const int lane = tid & 63;
    const int ln = lane & 31;
    const int h = lane >> 5;
    const int b = blockIdx.y >> 4;
    const int hh = blockIdx.y & 15;
    const int qbase = blockIdx.x * 128;

    const unsigned short* wsu = (const unsigned short*)(wsf + 128);

    bf16x8 akf[4], avf[4];
    #pragma unroll
    for (int c = 0; c < 4; c++) {
        int row = (w & 1) * 32 + ln;
        int col = c * 16 + h * 8;
        akf[c] = *(const bf16x8*)(wsu + 4096 + row * 64 + col);
        avf[c] = *(const bf16x8*)(wsu + 8192 + row * 64 + col);
    }
    const float ec0 = wsf[64 + ln];
    const float ec1 = wsf[96 + ln];

    bf16x8 qf[4];
    {
        bf16x8 xq[4];
        const float* xrow = x + ((size_t)(b * SEQ + qbase + w * 32 + ln) * DM + hh * HD);
        #pragma unroll
        for (int c = 0; c < 4; c++) {
            const float* p = xrow + c * 16 + h * 8;
            float4 f0 = *(const float4*)p;
            float4 f1 = *(const float4*)(p + 4);
            union { bf16x8 v; unsigned int u[4]; } t;
            t.u[0] = pk2t(f0.x, f0.y); t.u[1] = pk2t(f0.z, f0.w);
            t.u[2] = pk2t(f1.x, f1.y); t.u[3] = pk2t(f1.z, f1.w);
            xq[c] = t.v;
        }
        #pragma unroll
        for (int m = 0; m < 2; m++) {
            f32x16 acc;
            #pragma unroll
            for (int g = 0; g < 4; g++) {
                float4 b4 = *(const float4*)&wsf[m * 32 + 8 * g + 4 * h];
                acc[4 * g + 0] = b4.x; acc[4 * g + 1] = b4.y;
                acc[4 * g + 2] = b4.z; acc[4 * g + 3] = b4.w;
            }
            #pragma unroll
            for (int c = 0; c < 4; c++) {
                bf16x8 aq = *(const bf16x8*)(wsu + (m * 32 + ln) * 64 + c * 16 + h * 8);
                acc = MFMA32(aq, xq[c], acc, 0, 0, 0);
            }
            #pragma unroll
            for (int g = 0; g < 4; g++) {
                uint2 pw;
                pw.x = pk2r(acc[4 * g + 0], acc[4 * g + 1]);
                pw.y = pk2r(acc[4 * g + 2], acc[4 * g + 3]);
                *(uint2*)&ps_s[(w * 32 + ln) * 72 + m * 32 + 8 * g + 4 * h] = pw;
            }
        }
        #pragma unroll
        for (int c = 0; c < 4; c++)
            qf[c] = *(const bf16x8*)&ps_s[(w * 32 + ln) * 72 + c * 16 + h * 8];
    }

    f32x16 o0 = z16(), o1 = z16();
    float m_i = -1e30f, l_i = 0.f;

    const int krl = (w >> 1) * 32 + ln;
    const int dt32 = (w & 1) * 32;

    for (int kt = 0; kt < SEQ / 64; kt++) {
        bf16x8 xf[4];
        const float* xr = x + ((size_t)(b * SEQ + kt * 64 + krl) * DM + hh * HD);
        #pragma unroll
        for (int c = 0; c < 4; c++) {
            const float* p = xr + c * 16 + h * 8;
            float4 f0 = *(const float4*)p;
            float4 f1 = *(const float4*)(p + 4);
            union { bf16x8 v; unsigned int u[4]; } t;
            t.u[0] = pk2t(f0.x, f0.y); t.u[1] = pk2t(f0.z, f0.w);
            t.u[2] = pk2t(f1.x, f1.y); t.u[3] = pk2t(f1.z, f1.w);
            xf[c] = t.v;
        }
        f32x16 kacc = z16(), vacc = z16();
        #pragma unroll
        for (int c = 0; c < 4; c++) kacc = MFMA32(akf[c], xf[c], kacc, 0, 0, 0);
        #pragma unroll
        for (int c = 0; c < 4; c++) vacc = MFMA32(xf[c], avf[c], vacc, 0, 0, 0);
        #pragma unroll
        for (int g = 0; g < 4; g++) {
            uint2 pk_, pv_;
            pk_.x = pk2r(kacc[4 * g + 0], kacc[4 * g + 1]);
            pk_.y = pk2r(kacc[4 * g + 2], kacc[4 * g + 3]);
            *(uint2*)&ks_s[krl * 72 + dt32 + 8 * g + 4 * h] = pk_;
            pv_.x = pk2r(vacc[4 * g + 0], vacc[4 * g + 1]);
            pv_.y = pk2r(vacc[4 * g + 2], vacc[4 * g + 3]);
            *(uint2*)&vt_s[(dt32 + ln) * 72 + (w >> 1) * 32 + 8 * g + 4 * h] = pv_;
        }
        __syncthreads();

        f32x16 st0 = z16(), st1 = z16();
        #pragma unroll
        for (int c = 0; c < 4; c++) {
            bf16x8 k0 = *(const bf16x8*)&ks_s[ln * 72 + c * 16 + h * 8];
            bf16x8 k1 = *(const bf16x8*)&ks_s[(32 + ln) * 72 + c * 16 + h * 8];
            st0 = MFMA32(k0, qf[c], st0, 0, 0, 0);
            st1 = MFMA32(k1, qf[c], st1, 0, 0, 0);
        }
        float mx = st0[0];
        #pragma unroll
        for (int i = 1; i < 16; i++) mx = fmaxf(mx, st0[i]);
        #pragma unroll
        for (int i = 0; i < 16; i++) mx = fmaxf(mx, st1[i]);
        mx = fmaxf(mx, __shfl_xor(mx, 32));
        const float mn = fmaxf(m_i, mx);
        const float al = EXP2(m_i - mn);
        float ss = 0.f;
        #pragma unroll
        for (int i = 0; i < 16; i++) { st0[i] = EXP2(st0[i] - mn); ss += st0[i]; }
        #pragma unroll
        for (int i = 0; i < 16; i++) { st1[i] = EXP2(st1[i] - mn); ss += st1[i]; }
        ss += __shfl_xor(ss, 32);
        l_i = l_i * al + ss;
        m_i = mn;
        if (lane < 32) als_l[w * 32 + lane] = al;
        #pragma unroll
        for (int g = 0; g < 4; g++) {
            uint2 p0, p1;
            p0.x = pk2r(st0[4 * g + 0], st0[4 * g + 1]);
            p0.y = pk2r(st0[4 * g + 2], st0[4 * g + 3]);
            *(uint2*)&ps_s[(w * 32 + ln) * 72 + 8 * g + 4 * h] = p0;
            p1.x = pk2r(st1[4 * g + 0], st1[4 * g + 1]);
            p1.y = pk2r(st1[4 * g + 2], st1[4 * g + 3]);
            *(uint2*)&ps_s[(w * 32 + ln) * 72 + 32 + 8 * g + 4 * h] = p1;
        }
        #pragma unroll
        for (int g = 0; g < 4; g++) {
            float4 a4 = *(const float4*)&als_l[w * 32 + 8 * g + 4 * h];
            o0[4 * g + 0] *= a4.x; o0[4 * g + 1] *= a4.y;
            o0[4 * g + 2] *= a4.z; o0[4 * g + 3] *= a4.w;
            o1[4 * g + 0] *= a4.x; o1[4 * g + 1] *= a4.y;
            o1[4 * g + 2] *= a4.z; o1[4 * g + 3] *= a4.w;
        }
        #pragma unroll
        for (int c = 0; c < 4; c++) {
            bf16x8 pf = *(const bf16x8*)&ps_s[(w * 32 + ln) * 72 + c * 16 + h * 8];
            bf16x8 v0 = *(const bf16x8*)&vt_s[ln * 72 + c * 16 + h * 8];
            bf16x8 v1 = *(const bf16x8*)&vt_s[(32 + ln) * 72 + c * 16 + h * 8];
            o0 = MFMA32(pf, v0, o0, 0, 0, 0);
            o1 = MFMA32(pf, v1, o1, 0, 0, 0);
        }
        __syncthreads();
    }

    if (lane < 32) ls_l[w * 32 + lane] = l_i;
    #pragma unroll
    for (int g = 0; g < 4; g++) {
        float4 l4 = *(const float4*)&ls_l[w * 32 + 8 * g + 4 * h];
        float4 iv = make_float4(1.f / l4.x, 1.f / l4.y, 1.f / l4.z, 1.f / l4.w);
        #pragma unroll
        for (int i = 0; i < 4; i++) {
            float ivv = (i == 0) ? iv.x : (i == 1) ? iv.y : (i == 2) ? iv.z : iv.w;
            int q = qbase + w * 32 + 8 * g + 4 * h + i;
            float* orow = out + ((size_t)(b * SEQ + q) * DM + hh * HD);
            orow[ln] = o0[4 * g + i] * ivv + ec0;
            orow[32 + ln] = o1[4 * g + i] * ivv + ec1;
        }
    }
}

extern "C" void kernel_launch(void* const* d_in, const int* in_sizes, int n_in,
                              void* d_out, int out_size, void* d_ws, size_t ws_size,
                              hipStream_t stream) {
    const float* x = (const float*)d_in[0];
    float* wsf = (float*)d_ws;

    qmt_combine<<<3, 256, 0, stream>>>(
        (const float*)d_in[1],  (const float*)d_in[2],
        (const float*)d_in[3],  (const float*)d_in[4],
        (const float*)d_in[5],  (const float*)d_in[6],
        (const float*)d_in[7],  (const float*)d_in[8],
        (const float*)d_in[9],  (const float*)d_in[10],
        (const float*)d_in[11], (const float*)d_in[12],
        (const float*)d_in[13], (const float*)d_in[14],
        (const float*)d_in[15], (const float*)d_in[16],
        wsf);

    if (ws_size >= WS_NEED) {
        dim3 gkv(SEQ / 64, 64);
        qmt_kv<<<gkv, 256, 0, stream>>>(x, wsf);
        dim3 grid(SEQ / 128, 64);
        qmt_attn2<<<grid, 256, 0, stream>>>(x, wsf, (float*)d_out);
    } else {
        dim3 grid(SEQ / 128, 64);
        qmt_attn_fb<<<grid, 256, 0, stream>>>(x, wsf, (float*)d_out);
    }
}

// Round 2
// 227.973 us; speedup vs baseline: 1.0844x; 1.0663x over previous
//
#include <hip/hip_runtime.h>

// QuantumMotivicTile — B=4, S=2048, H=16, hd=64, D=1024, fp32 I/O.
// final = softmax(q k^T / 8) @ v'' + ecv
//   Aq = QS·Wq·Wi (QS = 0.125·log2e → scores in log2 domain, exp2 softmax),
//   Ak = Wk·Wi (bias cancels in softmax), Av = M·Wv·Wi, M = Wmi·Wm·Wci·Wc,
//   ecv = M·(Wv·bi+bv) + cvec.
// R7: K/V intermediate stored in PACKED MFMA C-layout (kv stores = contiguous
// 512B/wave, fully coalesced — fixes hidden scatter-write amplification that
// cost ~100µs); attn2 stages packed->LDS via ds_write_b128 transpose (stride-72
// layout = measured-good R5 inner loop, swizzle reverted); double-buffered LDS
// with 1 barrier/iter; XCD-swizzled 1-D grid; setprio around MFMA clusters.
// Kept from R6: register P/Q (cvt_pk+permlane32_swap), defer-max, tree reduces.

#define SEQ 2048
#define DM  1024
#define HD  64
#define QS  0.180336880111120429f  // 0.125 * log2(e)
#define THR 8.0f                   // defer-max threshold (log2 units)

typedef short bf16x8 __attribute__((ext_vector_type(8)));
typedef unsigned short u16x8 __attribute__((ext_vector_type(8)));
typedef float f32x16 __attribute__((ext_vector_type(16)));

#define MFMA32 __builtin_amdgcn_mfma_f32_32x32x16_bf16

#if defined(__has_builtin)
#if __has_builtin(__builtin_amdgcn_exp2f)
#define EXP2(x) __builtin_amdgcn_exp2f(x)
#endif
#endif
#ifndef EXP2
#define EXP2(x) exp2f(x)
#endif

// ws layout:
//   float [0..63] bq' (×QS), [64..127] ecv
//   ushort base wsu = (ushort*)(ws+128):
//     [0..4095]      Aq (×QS) row-major [dout][din]
//     [4096..8191]   Ak row-major
//     [8192..12287]  Av row-major
//     [12288 ..)     KgP[bh][kt][r][s]  packed C-layout (see below), 256KB/bh
//     [+8388608 ..)  VgP[bh][kt][r][s]  packed C-layout, 256KB/bh
// Packed tile (8KB = 1024 uint2): row r = w*4+g (0..15), slot s = 2*ln + h.
//   K: uint2(r, 2p+h') = K[key=(r>>3)*32+p][dout=((r>>2)&1)*32+(r&3)*8+4h'+0..3]
//   V: uint2(r, 2p+h') = V^T[dout=((r>>2)&1)*32+p][key=(r>>3)*32+(r&3)*8+4h'+0..3]
// => 16B pair p of row r is 8 consecutive douts (K) / keys (V): one ds_write_b128.
#define KG_OFF  12288
#define VG_OFF  (12288 + 8388608)
#define WS_NEED ((size_t)512 + 2ull * (12288 + 2ull * 8388608))

__device__ __forceinline__ unsigned short f2bf(float f) {
    unsigned int v = __float_as_uint(f);
    unsigned int r = v + 0x7FFFu + ((v >> 16) & 1u);
    return (unsigned short)(r >> 16);
}
__device__ __forceinline__ unsigned int pk2r(float a, float b) {
    return __builtin_amdgcn_perm(__float_as_uint(b) + 0x8000u,
                                 __float_as_uint(a) + 0x8000u, 0x07060302u);
}
__device__ __forceinline__ unsigned int pk2t(float a, float b) {
    return __builtin_amdgcn_perm(__float_as_uint(b), __float_as_uint(a), 0x07060302u);
}
// {lo: bf16(a), hi: bf16(b)} — RNE, 1 VALU op
__device__ __forceinline__ unsigned int cvtpk(float a, float b) {
    unsigned int r;
    asm("v_cvt_pk_bf16_f32 %0, %1, %2" : "=v"(r) : "v"(a), "v"(b));
    return r;
}
// a' = {a.lanes0-31, b.lanes0-31}; b' = {a.lanes32-63, b.lanes32-63}
__device__ __forceinline__ void swap32(unsigned int& a, unsigned int& b) {
    asm("v_permlane32_swap_b32 %0, %1" : "+v"(a), "+v"(b));
}
__device__ __forceinline__ f32x16 z16() {
    f32x16 v;
    #pragma unroll
    for (int i = 0; i < 16; i++) v[i] = 0.f;
    return v;
}

// 32x32 MFMA C-block -> two A/B-operand bf16 fragments (rows 0..15 / 16..31).
__device__ __forceinline__ void pack2(const f32x16 s, bf16x8& fA, bf16x8& fB) {
    union { bf16x8 v; unsigned int u[4]; } a, b;
    a.u[0] = cvtpk(s[0], s[1]);   a.u[1] = cvtpk(s[2], s[3]);
    a.u[2] = cvtpk(s[4], s[5]);   a.u[3] = cvtpk(s[6], s[7]);
    b.u[0] = cvtpk(s[8], s[9]);   b.u[1] = cvtpk(s[10], s[11]);
    b.u[2] = cvtpk(s[12], s[13]); b.u[3] = cvtpk(s[14], s[15]);
    swap32(a.u[0], a.u[2]); swap32(a.u[1], a.u[3]);
    swap32(b.u[0], b.u[2]); swap32(b.u[1], b.u[3]);
    fA = a.v; fB = b.v;
}

// acc[0..16) = (wrow · L)[i0..i0+16); wrow/L in LDS, row stride 68 floats
__device__ __forceinline__ void mm16L(const float* __restrict__ wrow,
                                      const float* __restrict__ L, int i0,
                                      float* __restrict__ acc) {
    #pragma unroll
    for (int ii = 0; ii < 16; ii++) acc[ii] = 0.f;
    for (int t = 0; t < 64; t += 4) {
        float4 w4 = *(const float4*)(wrow + t);
        #pragma unroll
        for (int d = 0; d < 4; d++) {
            float wv = (d == 0) ? w4.x : (d == 1) ? w4.y : (d == 2) ? w4.z : w4.w;
            const float* lr = L + (t + d) * 68 + i0;
            float4 a = *(const float4*)lr;
            float4 b = *(const float4*)(lr + 4);
            float4 c = *(const float4*)(lr + 8);
            float4 e = *(const float4*)(lr + 12);
            acc[0] += wv * a.x;  acc[1] += wv * a.y;  acc[2]  += wv * a.z;  acc[3]  += wv * a.w;
            acc[4] += wv * b.x;  acc[5] += wv * b.y;  acc[6]  += wv * b.z;  acc[7]  += wv * b.w;
            acc[8] += wv * c.x;  acc[9] += wv * c.y;  acc[10] += wv * c.z;  acc[11] += wv * c.w;
            acc[12] += wv * e.x; acc[13] += wv * e.y; acc[14] += wv * e.z;  acc[15] += wv * e.w;
        }
    }
}

// ---------------- weight folding (3 role blocks, 256 threads, all-LDS) ----------------
__global__ __launch_bounds__(256)
void qmt_combine(const float* __restrict__ Wi,  const float* __restrict__ bi,
                 const float* __restrict__ Wq,  const float* __restrict__ bq,
                 const float* __restrict__ Wk,  const float* __restrict__ bk,
                 const float* __restrict__ Wv,  const float* __restrict__ bv,
                 const float* __restrict__ Wc,  const float* __restrict__ bc,
                 const float* __restrict__ Wci, const float* __restrict__ bci,
                 const float* __restrict__ Wm,  const float* __restrict__ bm,
                 const float* __restrict__ Wmi, const float* __restrict__ bmi,
                 float* __restrict__ ws) {
    const int tid = threadIdx.x;
    const int o = tid & 63;
    const int i0 = (tid >> 6) * 16;
    const bool lead = (tid < 64);
    const int role = blockIdx.x;

    __shared__ float Wa_s[64 * 68];
    __shared__ float Wi_s[64 * 68];
    __shared__ float Wvi_s[64 * 68];
    __shared__ float M_s[64 * 68];
    __shared__ float Wc_s[512];
    __shared__ float Wci_s[512];
    __shared__ float Wm_s[256];
    __shared__ float Wmi_s[256];
    __shared__ float bi_s[64], bvi_s[64], c1[64], c2[4];
    __shared__ float U1[32], U2[256];

    unsigned short* wsu = (unsigned short*)(ws + 128);
    const float* Wa = (role == 0) ? Wq : (role == 1) ? Wk : Wv;

    for (int i4 = tid; i4 < 1024; i4 += 256) {
        int r = i4 >> 4, c = (i4 & 15) * 4;
        *(float4*)&Wi_s[r * 68 + c] = *(const float4*)(Wi + i4 * 4);
        *(float4*)&Wa_s[r * 68 + c] = *(const float4*)(Wa + i4 * 4);
    }
    if (role == 2) {
        if (tid < 128) {
            *(float4*)&Wc_s[tid * 4]  = *(const float4*)(Wc + tid * 4);
            *(float4*)&Wci_s[tid * 4] = *(const float4*)(Wci + tid * 4);
        } else if (tid < 192) {
            int t = tid - 128;
            *(float4*)&Wm_s[t * 4]  = *(const float4*)(Wm + t * 4);
            *(float4*)&Wmi_s[t * 4] = *(const float4*)(Wmi + t * 4);
        }
    }
    if (lead) bi_s[o] = bi[o];
    __syncthreads();  // (1)

    float acc[16];
    if (role == 0) {
        mm16L(Wa_s + o * 68, Wi_s, i0, acc);
        #pragma unroll
        for (int ii = 0; ii < 16; ii++) wsu[o * 64 + i0 + ii] = f2bf(acc[ii] * QS);
        if (lead) {
            float s = bq[o];
            for (int t = 0; t < 64; t++) s += Wa_s[o * 68 + t] * bi_s[t];
            ws[o] = s * QS;
        }
        return;
    }
    if (role == 1) {
        mm16L(Wa_s + o * 68, Wi_s, i0, acc);
        #pragma unroll
        for (int ii = 0; ii < 16; ii++) wsu[4096 + o * 64 + i0 + ii] = f2bf(acc[ii]);
        return;
    }
    mm16L(Wa_s + o * 68, Wi_s, i0, acc);
    #pragma unroll
    for (int ii = 0; ii < 16; ii++) Wvi_s[o * 68 + i0 + ii] = acc[ii];
    if (lead) {
        float s = bv[o];
        for (int t = 0; t < 64; t++) s += Wa_s[o * 68 + t] * bi_s[t];
        bvi_s[o] = s;
    }
    if (tid < 32) {
        int a = tid >> 3, c = tid & 7;
        float s = 0.f;
        for (int t = 0; t < 64; t++) s += Wm_s[a * 64 + t] * Wci_s[t * 8 + c];
        U1[a * 8 + c] = s;
    }
    __syncthreads();  // (2)
    if (lead) {
        for (int a = 0; a < 4; a++) {
            float s = 0.f;
            for (int cc = 0; cc < 8; cc++) s += U1[a * 8 + cc] * Wc_s[cc * 64 + o];
            U2[a * 64 + o] = s;
        }
        float s = bci[o];
        for (int j = 0; j < 8; j++) s += Wci_s[o * 8 + j] * bc[j];
        c1[o] = s;
    }
    __syncthreads();  // (3)
    #pragma unroll
    for (int ii = 0; ii < 16; ii++) {
        float s = 0.f;
        for (int a = 0; a < 4; a++) s += Wmi_s[o * 4 + a] * U2[a * 64 + i0 + ii];
        M_s[o * 68 + i0 + ii] = s;
    }
    if (tid < 4) {
        float s = bm[tid];
        for (int i = 0; i < 64; i++) s += Wm_s[tid * 64 + i] * c1[i];
        c2[tid] = s;
    }
    __syncthreads();  // (4)
    mm16L(M_s + o * 68, Wvi_s, i0, acc);
    #pragma unroll
    for (int ii = 0; ii < 16; ii++) wsu[8192 + o * 64 + i0 + ii] = f2bf(acc[ii]);
    if (lead) {
        float bvv = 0.f;
        for (int t = 0; t < 64; t++) bvv += M_s[o * 68 + t] * bvi_s[t];
        float cvv = bmi[o];
        for (int a = 0; a < 4; a++) cvv += Wmi_s[o * 4 + a] * c2[a];
        ws[64 + o] = cvv + bvv;
    }
}

// ---------------- KV prepass: grid (32, 64), 1 ktile/block ----------------
// Stores packed MFMA C-layout: each (w,g) store instr = contiguous 512B/wave.
__global__ __launch_bounds__(256)
void qmt_kv(const float* __restrict__ x, float* __restrict__ ws) {
    const int tid = threadIdx.x;
    const int w = tid >> 6;
    const int lane = tid & 63;
    const int ln = lane & 31;
    const int h = lane >> 5;
    const int b = blockIdx.y >> 4;
    const int hh = blockIdx.y & 15;
    const int kt = blockIdx.x;

    const unsigned short* wsu = (const unsigned short*)(ws + 128);
    unsigned short* Kg = (unsigned short*)(ws + 128) + KG_OFF + (size_t)blockIdx.y * (2048 * 64);
    unsigned short* Vg = (unsigned short*)(ws + 128) + VG_OFF + (size_t)blockIdx.y * (64 * 2048);

    const int krl = (w >> 1) * 32 + ln;
    const int dt32 = (w & 1) * 32;

    bf16x8 akf[4], avf[4];
    #pragma unroll
    for (int c = 0; c < 4; c++) {
        int row = dt32 + ln;
        int col = c * 16 + h * 8;
        akf[c] = *(const bf16x8*)(wsu + 4096 + row * 64 + col);
        avf[c] = *(const bf16x8*)(wsu + 8192 + row * 64 + col);
    }
    bf16x8 xf[4];
    const float* xr = x + ((size_t)(b * SEQ + kt * 64 + krl) * DM + hh * HD);
    #pragma unroll
    for (int c = 0; c < 4; c++) {
        const float* p = xr + c * 16 + h * 8;
        float4 f0 = *(const float4*)p;
        float4 f1 = *(const float4*)(p + 4);
        union { bf16x8 v; unsigned int u[4]; } tt;
        tt.u[0] = pk2t(f0.x, f0.y); tt.u[1] = pk2t(f0.z, f0.w);
        tt.u[2] = pk2t(f1.x, f1.y); tt.u[3] = pk2t(f1.z, f1.w);
        xf[c] = tt.v;
    }
    f32x16 kacc = z16(), vacc = z16();
    #pragma unroll
    for (int c = 0; c < 4; c++) kacc = MFMA32(akf[c], xf[c], kacc, 0, 0, 0);
    #pragma unroll
    for (int c = 0; c < 4; c++) vacc = MFMA32(xf[c], avf[c], vacc, 0, 0, 0);

    unsigned short* KgT = Kg + kt * 4096;  // 8KB packed tile
    unsigned short* VgT = Vg + kt * 4096;
    #pragma unroll
    for (int g = 0; g < 4; g++) {
        const int idx = (((w * 4 + g) * 64) + 2 * ln + h) * 4;  // ushort units
        uint2 pk_, pv_;
        pk_.x = cvtpk(kacc[4 * g + 0], kacc[4 * g + 1]);
        pk_.y = cvtpk(kacc[4 * g + 2], kacc[4 * g + 3]);
        *(uint2*)&KgT[idx] = pk_;
        pv_.x = cvtpk(vacc[4 * g + 0], vacc[4 * g + 1]);
        pv_.y = cvtpk(vacc[4 * g + 2], vacc[4 * g + 3]);
        *(uint2*)&VgT[idx] = pv_;
    }
}

// ---------------- MFMA flash attention ----------------
// 1-D grid 1024 (XCD-swizzled -> 16 q-tiles of a bh share one XCD's L2),
// 256 thr = 4 waves. QT=128, KT=64. Double-buffered LDS, 1 barrier/iter.
// Staging: packed global (contiguous 16KB/tile) -> ds_write_b128 transpose
// into stride-72 [key][dout]/[dout][key] tiles (measured-good R5 pattern).
__global__ __launch_bounds__(256, 4)
void qmt_attn2(const float* __restrict__ x, const float* __restrict__ wsf,
               float* __restrict__ out) {
    __shared__ __align__(16) unsigned short ks_s[2][64 * 72];  // K [key][dout]
    __shared__ __align__(16) unsigned short vt_s[2][64 * 72];  // V^T [dout][key]
    __shared__ float als_l[128];
    __shared__ float ls_l[128];

    const int tid = threadIdx.x;
    const int w = tid >> 6;
    const int lane = tid & 63;
    const int ln = lane & 31;
    const int h = lane >> 5;
    const int bid = blockIdx.x;
    const int wg = (bid & 7) * 128 + (bid >> 3);  // bijective XCD swizzle (1024 = 8*128)
    const int bh = wg >> 4;
    const int qbase = (wg & 15) * 128;
    const int b = bh >> 4;
    const int hh = bh & 15;

    const unsigned short* wsu = (const unsigned short*)(wsf + 128);
    const unsigned short* Kg = wsu + KG_OFF + (size_t)bh * (2048 * 64);
    const unsigned short* Vg = wsu + VG_OFF + (size_t)bh * (64 * 2048);

    const float ec0 = wsf[64 + ln];
    const float ec1 = wsf[96 + ln];

    // staging decode (loop-invariant): chunk i = pair p of packed row r
    const int r1 = tid >> 5, p1 = tid & 31, r2 = r1 + 8;
    const int ldsK1 = (((r1 >> 3) & 1) * 32 + p1) * 72 + ((r1 >> 2) & 1) * 32 + (r1 & 3) * 8;
    const int ldsK2 = (((r2 >> 3) & 1) * 32 + p1) * 72 + ((r2 >> 2) & 1) * 32 + (r2 & 3) * 8;
    const int ldsV1 = (((r1 >> 2) & 1) * 32 + p1) * 72 + ((r1 >> 3) & 1) * 32 + (r1 & 3) * 8;
    const int ldsV2 = (((r2 >> 2) & 1) * 32 + p1) * 72 + ((r2 >> 3) & 1) * 32 + (r2 & 3) * 8;
    const int gk1 = tid * 8;         // ushort offset of chunk i1 in packed tile
    const int gk2 = 2048 + tid * 8;  // chunk i2 (= i1 + 256 pairs)

    u16x8 ka, kb, va, vb;
    auto loadT = [&](int kt_) {
        const unsigned short* Kt = Kg + kt_ * 4096;
        const unsigned short* Vt = Vg + kt_ * 4096;
        ka = *(const u16x8*)(Kt + gk1);
        kb = *(const u16x8*)(Kt + gk2);
        va = *(const u16x8*)(Vt + gk1);
        vb = *(const u16x8*)(Vt + gk2);
    };
    auto storeT = [&](int bb) {
        *(u16x8*)&ks_s[bb][ldsK1] = ka;
        *(u16x8*)&ks_s[bb][ldsK2] = kb;
        *(u16x8*)&vt_s[bb][ldsV1] = va;
        *(u16x8*)&vt_s[bb][ldsV2] = vb;
    };

    loadT(0);  // tile-0 loads in flight under Q projection

    // ---- Q projection: Q^T = Aq·x^T (log2 scale folded in), all in registers ----
    bf16x8 qf[4];
    {
        bf16x8 xq[4];
        const float* xrow = x + ((size_t)(b * SEQ + qbase + w * 32 + ln) * DM + hh * HD);
        #pragma unroll
        for (int c = 0; c < 4; c++) {
            const float* p = xrow + c * 16 + h * 8;
            float4 f0 = *(const float4*)p;
            float4 f1 = *(const float4*)(p + 4);
            union { bf16x8 v; unsigned int u[4]; } t;
            t.u[0] = pk2t(f0.x, f0.y); t.u[1] = pk2t(f0.z, f0.w);
            t.u[2] = pk2t(f1.x, f1.y); t.u[3] = pk2t(f1.z, f1.w);
            xq[c] = t.v;
        }
        #pragma unroll
        for (int m = 0; m < 2; m++) {
            f32x16 acc;
            #pragma unroll
            for (int g = 0; g < 4; g++) {
                float4 b4 = *(const float4*)&wsf[m * 32 + 8 * g + 4 * h];
                acc[4 * g + 0] = b4.x; acc[4 * g + 1] = b4.y;
                acc[4 * g + 2] = b4.z; acc[4 * g + 3] = b4.w;
            }
            #pragma unroll
            for (int c = 0; c < 4; c++) {
                bf16x8 aq = *(const bf16x8*)(wsu + (m * 32 + ln) * 64 + c * 16 + h * 8);
                acc = MFMA32(aq, xq[c], acc, 0, 0, 0);
            }
            pack2(acc, qf[2 * m], qf[2 * m + 1]);
        }
    }

    f32x16 o0 = z16(), o1 = z16();
    float m_i = -1e30f, l_i = 0.f;

    storeT(0);
    loadT(1);
    __syncthreads();

    for (int kt = 0; kt < SEQ / 64; kt++) {
        const int cur = kt & 1;
        // write tile kt+1 into the other buffer (safe: prior barrier closed
        // all reads of that buffer), then issue loads for kt+2.
        if (kt + 1 < SEQ / 64) storeT(cur ^ 1);
        if (kt + 2 < SEQ / 64) loadT(kt + 2);

        const unsigned short* ks = ks_s[cur];
        const unsigned short* vt = vt_s[cur];

        // ---- S^T = K·Q^T (log2 domain) ----
        f32x16 st0 = z16(), st1 = z16();
        __builtin_amdgcn_s_setprio(1);
        #pragma unroll
        for (int c = 0; c < 4; c++) {
            bf16x8 k0 = *(const bf16x8*)&ks[ln * 72 + c * 16 + h * 8];
            bf16x8 k1 = *(const bf16x8*)&ks[(32 + ln) * 72 + c * 16 + h * 8];
            st0 = MFMA32(k0, qf[c], st0, 0, 0, 0);
            st1 = MFMA32(k1, qf[c], st1, 0, 0, 0);
        }
        __builtin_amdgcn_s_setprio(0);

        // tile max (tree)
        float tm[8];
        #pragma unroll
        for (int i = 0; i < 8; i++)
            tm[i] = fmaxf(fmaxf(st0[i], st0[i + 8]), fmaxf(st1[i], st1[i + 8]));
        #pragma unroll
        for (int i = 0; i < 4; i++) tm[i] = fmaxf(tm[i], tm[i + 4]);
        float mx = fmaxf(fmaxf(tm[0], tm[1]), fmaxf(tm[2], tm[3]));
        mx = fmaxf(mx, __shfl_xor(mx, 32));

        // defer-max: raise m / rescale only when some q grew by > THR
        const bool need = __any(mx > m_i + THR) != 0;
        float mn = m_i, al = 1.0f;
        if (need) {
            mn = fmaxf(m_i, mx);
            al = EXP2(m_i - mn);
            if (lane < 32) als_l[w * 32 + lane] = al;
        }

        #pragma unroll
        for (int i = 0; i < 16; i++) st0[i] = EXP2(st0[i] - mn);
        #pragma unroll
        for (int i = 0; i < 16; i++) st1[i] = EXP2(st1[i] - mn);
        float sm[8];
        #pragma unroll
        for (int i = 0; i < 8; i++)
            sm[i] = (st0[i] + st0[i + 8]) + (st1[i] + st1[i + 8]);
        #pragma unroll
        for (int i = 0; i < 4; i++) sm[i] += sm[i + 4];
        float ss = (sm[0] + sm[1]) + (sm[2] + sm[3]);
        ss += __shfl_xor(ss, 32);
        l_i = l_i * al + ss;
        m_i = mn;

        // P -> A-fragments, in registers
        bf16x8 pf[4];
        pack2(st0, pf[0], pf[1]);
        pack2(st1, pf[2], pf[3]);

        if (need) {
            #pragma unroll
            for (int g = 0; g < 4; g++) {
                float4 a4 = *(const float4*)&als_l[w * 32 + 8 * g + 4 * h];
                o0[4 * g + 0] *= a4.x; o0[4 * g + 1] *= a4.y;
                o0[4 * g + 2] *= a4.z; o0[4 * g + 3] *= a4.w;
                o1[4 * g + 0] *= a4.x; o1[4 * g + 1] *= a4.y;
                o1[4 * g + 2] *= a4.z; o1[4 * g + 3] *= a4.w;
            }
        }

        // ---- O += P·V ----
        __builtin_amdgcn_s_setprio(1);
        #pragma unroll
        for (int c = 0; c < 4; c++) {
            bf16x8 v0 = *(const bf16x8*)&vt[ln * 72 + c * 16 + h * 8];
            bf16x8 v1 = *(const bf16x8*)&vt[(32 + ln) * 72 + c * 16 + h * 8];
            o0 = MFMA32(pf[c], v0, o0, 0, 0, 0);
            o1 = MFMA32(pf[c], v1, o1, 0, 0, 0);
        }
        __builtin_amdgcn_s_setprio(0);

        __syncthreads();  // one barrier/iter: closes reads of cur AND publishes cur^1
    }

    // ---- epilogue ----
    if (lane < 32) ls_l[w * 32 + lane] = l_i;
    #pragma unroll
    for (int g = 0; g < 4; g++) {
        float4 l4 = *(const float4*)&ls_l[w * 32 + 8 * g + 4 * h];
        float4 iv = make_float4(1.f / l4.x, 1.f / l4.y, 1.f / l4.z, 1.f / l4.w);
        #pragma unroll
        for (int i = 0; i < 4; i++) {
            float ivv = (i == 0) ? iv.x : (i == 1) ? iv.y : (i == 2) ? iv.z : iv.w;
            int q = qbase + w * 32 + 8 * g + 4 * h + i;
            float* orow = out + ((size_t)(b * SEQ + q) * DM + hh * HD);
            orow[ln] = o0[4 * g + i] * ivv + ec0;
            orow[32 + ln] = o1[4 * g + i] * ivv + ec1;
        }
    }
}

// ---------------- fallback attention (in-loop KV projection) ----------------
__global__ __launch_bounds__(256, 3)
void qmt_attn_fb(const float* __restrict__ x, const float* __restrict__ wsf,
                 float* __restrict__ out) {
    __shared__ __align__(16) unsigned short ps_s[128 * 72];
    __shared__ __align__(16) unsigned short ks_s[64 * 72];
    __shared__ __align__(16) unsigned short vt_s[64 * 72];
    __shared__ float als_l[128];
    __shared__ float ls_l[128];

    const int tid = threadIdx.x;
    const int w = tid >> 6;
    const int lane = tid & 63;
    const int ln = lane & 31;
    const int h = lane >> 5;
    const int b = blockIdx.y >> 4;
    const int hh = blockIdx.y & 15;
    const int qbase = blockIdx.x * 128;

    const unsigned short* wsu = (const unsigned short*)(wsf + 128);

    bf16x8 akf[4], avf[4];
    #pragma unroll
    for (int c = 0; c < 4; c++) {
        int row = (w & 1) * 32 + ln;
        int col = c * 16 + h * 8;
        akf[c] = *(const bf16x8*)(wsu + 4096 + row * 64 + col);
        avf[c] = *(const bf16x8*)(wsu + 8192 + row * 64 + col);
    }
    const float ec0 = wsf[64 + ln];
    const float ec1 = wsf[96 + ln];

    bf16x8 qf[4];
    {
        bf16x8 xq[4];
        const float* xrow = x + ((size_t)(b * SEQ + qbase + w * 32 + ln) * DM + hh * HD);
        #pragma unroll
        for (int c = 0; c < 4; c++) {
            const float* p = xrow + c * 16 + h * 8;
            float4 f0 = *(const float4*)p;
            float4 f1 = *(const float4*)(p + 4);
            union { bf16x8 v; unsigned int u[4]; } t;
            t.u[0] = pk2t(f0.x, f0.y); t.u[1] = pk2t(f0.z, f0.w);
            t.u[2] = pk2t(f1.x, f1.y); t.u[3] = pk2t(f1.z, f1.w);
            xq[c] = t.v;
        }
        #pragma unroll
        for (int m = 0; m < 2; m++) {
            f32x16 acc;
            #pragma unroll
            for (int g = 0; g < 4; g++) {
                float4 b4 = *(const float4*)&wsf[m * 32 + 8 * g + 4 * h];
                acc[4 * g + 0] = b4.x; acc[4 * g + 1] = b4.y;
                acc[4 * g + 2] = b4.z; acc[4 * g + 3] = b4.w;
            }
            #pragma unroll
            for (int c = 0; c < 4; c++) {
                bf16x8 aq = *(const bf16x8*)(wsu + (m * 32 + ln) * 64 + c * 16 + h * 8);
                acc = MFMA32(aq, xq[c], acc, 0, 0, 0);
            }
            #pragma unroll
            for (int g = 0; g < 4; g++) {
                uint2 pw;
                pw.x = pk2r(acc[4 * g + 0], acc[4 * g + 1]);
                pw.y = pk2r(acc[4 * g + 2], acc[4 * g + 3]);
                *(uint2*)&ps_s[(w * 32 + ln) * 72 + m * 32 + 8 * g + 4 * h] = pw;
            }
        }
        #pragma unroll
        for (int c = 0; c < 4; c++)
            qf[c] = *(const bf16x8*)&ps_s[(w * 32 + ln) * 72 + c * 16 + h * 8];
    }

    f32x16 o0 = z16(), o1 = z16();
    float m_i = -1e30f, l_i = 0.f;

    const int krl = (w >> 1) * 32 + ln;
    const int dt32 = (w & 1) * 32;

    for (int kt = 0; kt < SEQ / 64; kt++) {
        bf16x8 xf[4];
        const float* xr = x + ((size_t)(b * SEQ + kt * 64 + krl) * DM + hh * HD);
        #pragma unroll
        for (int c = 0; c < 4; c++) {
            const float* p = xr + c * 16 + h * 8;
            float4 f0 = *(const float4*)p;
            float4 f1 = *(const float4*)(p + 4);
            union { bf16x8 v; unsigned int u[4]; } t;
            t.u[0] = pk2t(f0.x, f0.y); t.u[1] = pk2t(f0.z, f0.w);
            t.u[2] = pk2t(f1.x, f1.y); t.u[3] = pk2t(f1.z, f1.w);
            xf[c] = t.v;
        }
        f32x16 kacc = z16(), vacc = z16();
        #pragma unroll
        for (int c = 0; c < 4; c++) kacc = MFMA32(akf[c], xf[c], kacc, 0, 0, 0);
        #pragma unroll
        for (int c = 0; c < 4; c++) vacc = MFMA32(xf[c], avf[c], vacc, 0, 0, 0);
        #pragma unroll
        for (int g = 0; g < 4; g++) {
            uint2 pk_, pv_;
            pk_.x = pk2r(kacc[4 * g + 0], kacc[4 * g + 1]);
            pk_.y = pk2r(kacc[4 * g + 2], kacc[4 * g + 3]);
            *(uint2*)&ks_s[krl * 72 + dt32 + 8 * g + 4 * h] = pk_;
            pv_.x = pk2r(vacc[4 * g + 0], vacc[4 * g + 1]);
            pv_.y = pk2r(vacc[4 * g + 2], vacc[4 * g + 3]);
            *(uint2*)&vt_s[(dt32 + ln) * 72 + (w >> 1) * 32 + 8 * g + 4 * h] = pv_;
        }
        __syncthreads();

        f32x16 st0 = z16(), st1 = z16();
        #pragma unroll
        for (int c = 0; c < 4; c++) {
            bf16x8 k0 = *(const bf16x8*)&ks_s[ln * 72 + c * 16 + h * 8];
            bf16x8 k1 = *(const bf16x8*)&ks_s[(32 + ln) * 72 + c * 16 + h * 8];
            st0 = MFMA32(k0, qf[c], st0, 0, 0, 0);
            st1 = MFMA32(k1, qf[c], st1, 0, 0, 0);
        }
        float mx = st0[0];
        #pragma unroll
        for (int i = 1; i < 16; i++) mx = fmaxf(mx, st0[i]);
        #pragma unroll
        for (int i = 0; i < 16; i++) mx = fmaxf(mx, st1[i]);
        mx = fmaxf(mx, __shfl_xor(mx, 32));
        const float mn = fmaxf(m_i, mx);
        const float al = EXP2(m_i - mn);
        float ss = 0.f;
        #pragma unroll
        for (int i = 0; i < 16; i++) { st0[i] = EXP2(st0[i] - mn); ss += st0[i]; }
        #pragma unroll
        for (int i = 0; i < 16; i++) { st1[i] = EXP2(st1[i] - mn); ss += st1[i]; }
        ss += __shfl_xor(ss, 32);
        l_i = l_i * al + ss;
        m_i = mn;
        if (lane < 32) als_l[w * 32 + lane] = al;
        #pragma unroll
        for (int g = 0; g < 4; g++) {
            uint2 p0, p1;
            p0.x = pk2r(st0[4 * g + 0], st0[4 * g + 1]);
            p0.y = pk2r(st0[4 * g + 2], st0[4 * g + 3]);
            *(uint2*)&ps_s[(w * 32 + ln) * 72 + 8 * g + 4 * h] = p0;
            p1.x = pk2r(st1[4 * g + 0], st1[4 * g + 1]);
            p1.y = pk2r(st1[4 * g + 2], st1[4 * g + 3]);
            *(uint2*)&ps_s[(w * 32 + ln) * 72 + 32 + 8 * g + 4 * h] = p1;
        }
        #pragma unroll
        for (int g = 0; g < 4; g++) {
            float4 a4 = *(const float4*)&als_l[w * 32 + 8 * g + 4 * h];
            o0[4 * g + 0] *= a4.x; o0[4 * g + 1] *= a4.y;
            o0[4 * g + 2] *= a4.z; o0[4 * g + 3] *= a4.w;
            o1[4 * g + 0] *= a4.x; o1[4 * g + 1] *= a4.y;
            o1[4 * g + 2] *= a4.z; o1[4 * g + 3] *= a4.w;
        }
        #pragma unroll
        for (int c = 0; c < 4; c++) {
            bf16x8 pf = *(const bf16x8*)&ps_s[(w * 32 + ln) * 72 + c * 16 + h * 8];
            bf16x8 v0 = *(const bf16x8*)&vt_s[ln * 72 + c * 16 + h * 8];
            bf16x8 v1 = *(const bf16x8*)&vt_s[(32 + ln) * 72 + c * 16 + h * 8];
            o0 = MFMA32(pf, v0, o0, 0, 0, 0);
            o1 = MFMA32(pf, v1, o1, 0, 0, 0);
        }
        __syncthreads();
    }

    if (lane < 32) ls_l[w * 32 + lane] = l_i;
    #pragma unroll
    for (int g = 0; g < 4; g++) {
        float4 l4 = *(const float4*)&ls_l[w * 32 + 8 * g + 4 * h];
        float4 iv = make_float4(1.f / l4.x, 1.f / l4.y, 1.f / l4.z, 1.f / l4.w);
        #pragma unroll
        for (int i = 0; i < 4; i++) {
            float ivv = (i == 0) ? iv.x : (i == 1) ? iv.y : (i == 2) ? iv.z : iv.w;
            int q = qbase + w * 32 + 8 * g + 4 * h + i;
            float* orow = out + ((size_t)(b * SEQ + q) * DM + hh * HD);
            orow[ln] = o0[4 * g + i] * ivv + ec0;
            orow[32 + ln] = o1[4 * g + i] * ivv + ec1;
        }
    }
}

extern "C" void kernel_launch(void* const* d_in, const int* in_sizes, int n_in,
                              void* d_out, int out_size, void* d_ws, size_t ws_size,
                              hipStream_t stream) {
    const float* x = (const float*)d_in[0];
    float* wsf = (float*)d_ws;

    qmt_combine<<<3, 256, 0, stream>>>(
        (const float*)d_in[1],  (const float*)d_in[2],
        (const float*)d_in[3],  (const float*)d_in[4],
        (const float*)d_in[5],  (const float*)d_in[6],
        (const float*)d_in[7],  (const float*)d_in[8],
        (const float*)d_in[9],  (const float*)d_in[10],
        (const float*)d_in[11], (const float*)d_in[12],
        (const float*)d_in[13], (const float*)d_in[14],
        (const float*)d_in[15], (const float*)d_in[16],
        wsf);

    if (ws_size >= WS_NEED) {
        dim3 gkv(SEQ / 64, 64);
        qmt_kv<<<gkv, 256, 0, stream>>>(x, wsf);
        qmt_attn2<<<1024, 256, 0, stream>>>(x, wsf, (float*)d_out);
    } else {
        dim3 grid(SEQ / 128, 64);
        qmt_attn_fb<<<grid, 256, 0, stream>>>(x, wsf, (float*)d_out);
    }
}